// Round 2
// baseline (226.998 us; speedup 1.0000x reference)
//
#include <hip/hip_runtime.h>
#include <hip/hip_bf16.h>
#include <cmath>

// Problem constants (AddictiveAttention): B=32, C=512, H=W=32 (HW=1024), HID=256, MEM=256
// Inputs : x[32,512,32,32] f32, h[32,256], W_conv1[256,512], W_lin[256,256], b_lin[256], W_attn[256]
// Outputs: a3[32,1024] then context[32,512], concatenated f32 in d_out.

#define BK 32
#define TILE_S 64

// ---------------- Kernel A: h3[b][k] = dot(h[b], W_lin[k]) + b_lin[k] ----------------
__global__ __launch_bounds__(256) void h3_kernel(const float* __restrict__ h,
                                                 const float* __restrict__ Wlin,
                                                 const float* __restrict__ blin,
                                                 float* __restrict__ h3) {
    const int b = blockIdx.x;
    const int k = threadIdx.x;
    __shared__ float hs[256];
    hs[k] = h[b * 256 + k];
    __syncthreads();
    const float4* wr = (const float4*)(Wlin + (size_t)k * 256);
    float acc = blin[k];
    #pragma unroll 8
    for (int q = 0; q < 64; ++q) {
        float4 w = wr[q];
        float4 hv = *(const float4*)&hs[q * 4];
        acc = fmaf(w.x, hv.x, fmaf(w.y, hv.y, fmaf(w.z, hv.z, fmaf(w.w, hv.w, acc))));
    }
    h3[b * 256 + k] = acc;
}

// ---------------- Kernel B: fused 1x1-conv GEMM + tanh + W_attn reduce -> a2[b][s] ----
// Per block: batch b, spatial tile of 64 columns, ALL 256 output channels.
// x3[k,s] = sum_c W_conv1[k,c] * x[b,c,s];  a2[s] = sum_k W_attn[k]*tanh(x3[k,s]+h3[b,k])
__global__ __launch_bounds__(256) void fused_attn_logits(const float* __restrict__ x,
                                                         const float* __restrict__ Wc,
                                                         const float* __restrict__ h3,
                                                         const float* __restrict__ Wattn,
                                                         float* __restrict__ a2) {
    __shared__ float Wlds[BK][256];     // transposed chunk: Wlds[c][k]   (32 KiB)
    __shared__ float xlds[BK][TILE_S];  // xlds[c][s]                     (8 KiB)

    const int tid = threadIdx.x;
    const int b  = blockIdx.y;          // 0..31
    const int s0 = blockIdx.x * TILE_S; // 16 tiles
    const int ik = tid & 63;            // k-group: covers k = ik*4 .. ik*4+3
    const int j  = tid >> 6;            // wave id 0..3 -> s sub-block j*16

    float acc[4][16];
    #pragma unroll
    for (int r = 0; r < 4; ++r)
        #pragma unroll
        for (int t = 0; t < 16; ++t) acc[r][t] = 0.f;

    const float* xb = x + ((size_t)b << 19); // b*512*1024

    for (int c0 = 0; c0 < 512; c0 += BK) {
        // ---- load staging registers (global) ----
        const float4* wsrc = (const float4*)(Wc + (size_t)tid * 512 + c0);
        float4 wv[8];
        #pragma unroll
        for (int q = 0; q < 8; ++q) wv[q] = wsrc[q];

        float4 xv[2];
        #pragma unroll
        for (int q = 0; q < 2; ++q) {
            int l = q * 256 + tid;          // 0..511
            int c = l >> 4;                 // 0..31
            int sp = (l & 15) << 2;         // 0..60
            xv[q] = *(const float4*)(xb + (size_t)(c0 + c) * 1024 + s0 + sp);
        }

        __syncthreads(); // previous chunk's compute done before overwriting LDS
        #pragma unroll
        for (int q = 0; q < 8; ++q) {
            int cc = q * 4;
            Wlds[cc + 0][tid] = wv[q].x;
            Wlds[cc + 1][tid] = wv[q].y;
            Wlds[cc + 2][tid] = wv[q].z;
            Wlds[cc + 3][tid] = wv[q].w;
        }
        #pragma unroll
        for (int q = 0; q < 2; ++q) {
            int l = q * 256 + tid;
            int c = l >> 4;
            int sp = (l & 15) << 2;
            *(float4*)&xlds[c][sp] = xv[q];
        }
        __syncthreads();

        // ---- compute: 32 c-steps, 4k x 16s micro-tile per thread ----
        #pragma unroll 4
        for (int c = 0; c < BK; ++c) {
            float4 w4 = *(const float4*)&Wlds[c][ik * 4]; // contiguous b128, conflict-free
            float wa[4] = {w4.x, w4.y, w4.z, w4.w};
            float4 x4[4];
            #pragma unroll
            for (int t = 0; t < 4; ++t)
                x4[t] = *(const float4*)&xlds[c][j * 16 + t * 4]; // wave-uniform: broadcast
            #pragma unroll
            for (int r = 0; r < 4; ++r) {
                #pragma unroll
                for (int t = 0; t < 4; ++t) {
                    acc[r][t * 4 + 0] = fmaf(wa[r], x4[t].x, acc[r][t * 4 + 0]);
                    acc[r][t * 4 + 1] = fmaf(wa[r], x4[t].y, acc[r][t * 4 + 1]);
                    acc[r][t * 4 + 2] = fmaf(wa[r], x4[t].z, acc[r][t * 4 + 2]);
                    acc[r][t * 4 + 3] = fmaf(wa[r], x4[t].w, acc[r][t * 4 + 3]);
                }
            }
        }
    }

    // ---- epilogue: tanh + W_attn partial reduce ----
    const float* h3b = h3 + b * 256;
    float part[16];
    #pragma unroll
    for (int t = 0; t < 16; ++t) part[t] = 0.f;
    #pragma unroll
    for (int r = 0; r < 4; ++r) {
        int k = ik * 4 + r;
        float hv = h3b[k];
        float wat = Wattn[k];
        #pragma unroll
        for (int t = 0; t < 16; ++t)
            part[t] += wat * tanhf(acc[r][t] + hv);
    }
    // butterfly across all 64 lanes (k covered per-wave; each wave has same s columns)
    #pragma unroll
    for (int off = 32; off >= 1; off >>= 1) {
        #pragma unroll
        for (int t = 0; t < 16; ++t)
            part[t] += __shfl_xor(part[t], off, 64);
    }
    const int lane = tid & 63;
    // static-index select (avoid runtime-indexed array -> scratch)
    float out = 0.f;
    #pragma unroll
    for (int t = 0; t < 16; ++t) out = (lane == t) ? part[t] : out;
    if (lane < 16)
        a2[(size_t)b * 1024 + s0 + j * 16 + lane] = out;
}

// ---------------- Kernel C: row softmax over 1024 ----------------
__global__ __launch_bounds__(256) void softmax_kernel(const float* __restrict__ a2,
                                                      float* __restrict__ a3) {
    const int b = blockIdx.x;
    const int tid = threadIdx.x;
    __shared__ float red[8];
    float4 v = ((const float4*)(a2 + (size_t)b * 1024))[tid];
    float m = fmaxf(fmaxf(v.x, v.y), fmaxf(v.z, v.w));
    #pragma unroll
    for (int off = 32; off >= 1; off >>= 1) m = fmaxf(m, __shfl_xor(m, off, 64));
    const int wave = tid >> 6, lane = tid & 63;
    if (lane == 0) red[wave] = m;
    __syncthreads();
    m = fmaxf(fmaxf(red[0], red[1]), fmaxf(red[2], red[3]));
    float e0 = expf(v.x - m), e1 = expf(v.y - m), e2 = expf(v.z - m), e3 = expf(v.w - m);
    float s = e0 + e1 + e2 + e3;
    #pragma unroll
    for (int off = 32; off >= 1; off >>= 1) s += __shfl_xor(s, off, 64);
    if (lane == 0) red[4 + wave] = s;
    __syncthreads();
    s = red[4] + red[5] + red[6] + red[7];
    float inv = 1.f / s;
    float4 o = {e0 * inv, e1 * inv, e2 * inv, e3 * inv};
    ((float4*)(a3 + (size_t)b * 1024))[tid] = o;
}

// ---------------- Kernel D: context[b][c] = sum_s x[b][c][s] * a3[b][s] ----------------
__global__ __launch_bounds__(256) void context_kernel(const float* __restrict__ x,
                                                      const float* __restrict__ a3,
                                                      float* __restrict__ ctx) {
    __shared__ float a3s[1024];
    const int tid = threadIdx.x;
    const int b = blockIdx.y;
    const int ct = blockIdx.x; // 16 tiles x 32 rows
    #pragma unroll
    for (int q = 0; q < 4; ++q) a3s[q * 256 + tid] = a3[(size_t)b * 1024 + q * 256 + tid];
    __syncthreads();
    const int wave = tid >> 6, lane = tid & 63;
    const float* xb = x + ((size_t)b << 19);
    #pragma unroll
    for (int r = 0; r < 8; ++r) {
        int c = ct * 32 + wave * 8 + r;
        const float4* row = (const float4*)(xb + (size_t)c * 1024);
        float sum = 0.f;
        #pragma unroll
        for (int it = 0; it < 4; ++it) {
            int idx = it * 64 + lane;
            float4 v = row[idx];
            float4 a = *(const float4*)&a3s[idx * 4];
            sum = fmaf(v.x, a.x, fmaf(v.y, a.y, fmaf(v.z, a.z, fmaf(v.w, a.w, sum))));
        }
        #pragma unroll
        for (int off = 32; off >= 1; off >>= 1) sum += __shfl_xor(sum, off, 64);
        if (lane == 0) ctx[(size_t)b * 512 + c] = sum;
    }
}

extern "C" void kernel_launch(void* const* d_in, const int* in_sizes, int n_in,
                              void* d_out, int out_size, void* d_ws, size_t ws_size,
                              hipStream_t stream) {
    const float* x     = (const float*)d_in[0];
    const float* h     = (const float*)d_in[1];
    const float* Wc    = (const float*)d_in[2];
    const float* Wlin  = (const float*)d_in[3];
    const float* blin  = (const float*)d_in[4];
    const float* Wattn = (const float*)d_in[5];

    float* out = (float*)d_out;
    float* a3  = out;               // 32*1024
    float* ctx = out + 32 * 1024;   // 32*512

    float* h3 = (float*)d_ws;       // 8192 floats
    float* a2 = h3 + 8192;          // 32768 floats

    hipLaunchKernelGGL(h3_kernel, dim3(32), dim3(256), 0, stream, h, Wlin, blin, h3);
    hipLaunchKernelGGL(fused_attn_logits, dim3(16, 32), dim3(256), 0, stream, x, Wc, h3, Wattn, a2);
    hipLaunchKernelGGL(softmax_kernel, dim3(32), dim3(256), 0, stream, a2, a3);
    hipLaunchKernelGGL(context_kernel, dim3(16, 32), dim3(256), 0, stream, x, a3, ctx);
}

// Round 6
// 162.740 us; speedup vs baseline: 1.3948x; 1.3948x over previous
//
#include <hip/hip_runtime.h>
#include <hip/hip_bf16.h>
#include <cmath>

// AddictiveAttention: B=32, C=512, HW=1024, HID=256, MEM=256
// out = [a3: 32*1024 | context: 32*512] f32
//
// Pipeline:
//  K0 memset a2=0
//  K1 prep: h3[b][k] = h@Wlin.T + blin ; W_conv1 -> Whi/Wlo bf16 split
//  K2 fused_mfma: x3 = W@x via 3-term split-bf16 MFMA, +h3, tanh, *Wattn,
//                 reduce over k -> atomicAdd a2[b][s]
//  K3 softmax_context: per-block softmax(a2[b]) -> a3 (ct==0 writes), context

typedef __bf16 bf16;
typedef __attribute__((ext_vector_type(8))) __bf16 bf16x8;
typedef __attribute__((ext_vector_type(4))) float f32x4;

// ---------------- K1: prep (h3 + W split) ----------------
__global__ __launch_bounds__(256) void prep_kernel(const float* __restrict__ h,
                                                   const float* __restrict__ Wlin,
                                                   const float* __restrict__ blin,
                                                   const float* __restrict__ Wc,
                                                   float* __restrict__ h3,
                                                   bf16* __restrict__ Whi,
                                                   bf16* __restrict__ Wlo) {
    const int tid = threadIdx.x;
    if (blockIdx.x < 32) {
        const int b = blockIdx.x;
        __shared__ float hs[256];
        hs[tid] = h[b * 256 + tid];
        __syncthreads();
        const float4* wr = (const float4*)(Wlin + (size_t)tid * 256);
        float acc = blin[tid];
        #pragma unroll 8
        for (int q = 0; q < 64; ++q) {
            float4 w = wr[q];
            float4 hv = *(const float4*)&hs[q * 4];
            acc = fmaf(w.x, hv.x, fmaf(w.y, hv.y, fmaf(w.z, hv.z, fmaf(w.w, hv.w, acc))));
        }
        h3[b * 256 + tid] = acc;
    } else {
        const int e0 = (blockIdx.x - 32) * 2048 + tid * 8;
        float4 v0 = *(const float4*)(Wc + e0);
        float4 v1 = *(const float4*)(Wc + e0 + 4);
        float vs[8] = {v0.x, v0.y, v0.z, v0.w, v1.x, v1.y, v1.z, v1.w};
        bf16x8 vh, vl;
        #pragma unroll
        for (int j = 0; j < 8; ++j) {
            bf16 hi = (bf16)vs[j];
            float r = vs[j] - (float)hi;
            vh[j] = hi;
            vl[j] = (bf16)r;
        }
        *(bf16x8*)&Whi[e0] = vh;
        *(bf16x8*)&Wlo[e0] = vl;
    }
}

// ---------------- K2: split-bf16 MFMA GEMM + tanh + Wattn reduce ----------------
// Per block: m-half (128 k-chans) x 64 s-cols of one batch. 4 waves, each 32 k-rows.
// LDS XOR-swizzle: ushort idx col ^= 8*(row&7)  (write and read both swizzled).
__global__ __launch_bounds__(256, 3) void fused_mfma(const float* __restrict__ x,
                                                     const bf16* __restrict__ Whi,
                                                     const bf16* __restrict__ Wlo,
                                                     const float* __restrict__ h3,
                                                     const float* __restrict__ Wattn,
                                                     float* __restrict__ a2) {
    __shared__ bf16 Ahi[128 * 64];
    __shared__ bf16 Alo[128 * 64];
    __shared__ bf16 Bhi[64 * 64];
    __shared__ bf16 Blo[64 * 64];
    __shared__ float red2[4 * 64];

    const int tid = threadIdx.x;
    const int bid = blockIdx.x;
    // XCD-chunked swizzle (1024 % 8 == 0 -> bijective): each XCD gets 4 whole batches
    const int wk = (bid & 7) * 128 + (bid >> 3);
    const int b  = wk >> 5;
    const int st = (wk >> 1) & 15;
    const int mb = wk & 1;
    const int s0 = st * 64;
    const int r0 = mb * 128;

    const int w  = tid >> 6;   // wave 0..3 -> k-rows [w*32, w*32+32)
    const int l  = tid & 63;
    const int g  = l >> 4;     // k-group within frag
    const int lr = l & 15;

    const float* xb = x + ((size_t)b << 19);

    f32x4 acc[2][4];
    #pragma unroll
    for (int mf = 0; mf < 2; ++mf)
        #pragma unroll
        for (int nf = 0; nf < 4; ++nf)
            acc[mf][nf] = (f32x4){0.f, 0.f, 0.f, 0.f};

    const int arow_ = tid >> 3;        // A stage: row base (+32j)
    const int acol  = (tid & 7) * 8;   // A stage: ushort chunk start
    const int bs    = (tid >> 3) * 2;  // B stage: s-pair
    const int bc_   = (tid & 7) * 2;   // B stage: c-pair base (+16j)

    #pragma unroll 1
    for (int c0 = 0; c0 < 512; c0 += 64) {
        // -- global loads to regs --
        bf16x8 wva[4], wvl[4];
        #pragma unroll
        for (int jj = 0; jj < 4; ++jj) {
            int row = arow_ + 32 * jj;
            size_t off = (size_t)(r0 + row) * 512 + c0 + acol;
            wva[jj] = *(const bf16x8*)(Whi + off);
            wvl[jj] = *(const bf16x8*)(Wlo + off);
        }
        float2 xv0[4], xv1[4];
        #pragma unroll
        for (int jj = 0; jj < 4; ++jj) {
            int cc = bc_ + 16 * jj;
            xv0[jj] = *(const float2*)(xb + (size_t)(c0 + cc) * 1024 + s0 + bs);
            xv1[jj] = *(const float2*)(xb + (size_t)(c0 + cc + 1) * 1024 + s0 + bs);
        }
        __syncthreads();  // previous tile's compute done
        // -- LDS writes (swizzled) --
        #pragma unroll
        for (int jj = 0; jj < 4; ++jj) {
            int row = arow_ + 32 * jj;
            int idx = row * 64 + (acol ^ (8 * (row & 7)));
            *(bf16x8*)&Ahi[idx] = wva[jj];
            *(bf16x8*)&Alo[idx] = wvl[jj];
        }
        #pragma unroll
        for (int jj = 0; jj < 4; ++jj) {
            int cc = bc_ + 16 * jj;
            // 2x2 block: rows bs,bs+1 x cols cc,cc+1
            bf16 h00 = (bf16)xv0[jj].x, h10 = (bf16)xv1[jj].x;  // row bs
            bf16 h01 = (bf16)xv0[jj].y, h11 = (bf16)xv1[jj].y;  // row bs+1
            bf16 l00 = (bf16)(xv0[jj].x - (float)h00), l10 = (bf16)(xv1[jj].x - (float)h10);
            bf16 l01 = (bf16)(xv0[jj].y - (float)h01), l11 = (bf16)(xv1[jj].y - (float)h11);
            int i0 = bs * 64 + (cc ^ (8 * (bs & 7)));
            int i1 = (bs + 1) * 64 + (cc ^ (8 * ((bs + 1) & 7)));
            Bhi[i0] = h00; Bhi[i0 + 1] = h10;
            Blo[i0] = l00; Blo[i0 + 1] = l10;
            Bhi[i1] = h01; Bhi[i1 + 1] = h11;
            Blo[i1] = l01; Blo[i1 + 1] = l11;
        }
        __syncthreads();  // tile ready
        // -- compute: 2 K-steps x (2 mf x 4 nf x 3 terms) MFMA --
        #pragma unroll
        for (int kk = 0; kk < 2; ++kk) {
            bf16x8 ah[2], al[2], bh[4], bl[4];
            #pragma unroll
            for (int mf = 0; mf < 2; ++mf) {
                int row = w * 32 + mf * 16 + lr;
                int idx = row * 64 + ((kk * 32 + 8 * g) ^ (8 * (row & 7)));
                ah[mf] = *(const bf16x8*)&Ahi[idx];
                al[mf] = *(const bf16x8*)&Alo[idx];
            }
            #pragma unroll
            for (int nf = 0; nf < 4; ++nf) {
                int srow = nf * 16 + lr;
                int idx = srow * 64 + ((kk * 32 + 8 * g) ^ (8 * (srow & 7)));
                bh[nf] = *(const bf16x8*)&Bhi[idx];
                bl[nf] = *(const bf16x8*)&Blo[idx];
            }
            #pragma unroll
            for (int mf = 0; mf < 2; ++mf)
                #pragma unroll
                for (int nf = 0; nf < 4; ++nf) {
                    acc[mf][nf] = __builtin_amdgcn_mfma_f32_16x16x32_bf16(ah[mf], bh[nf], acc[mf][nf], 0, 0, 0);
                    acc[mf][nf] = __builtin_amdgcn_mfma_f32_16x16x32_bf16(ah[mf], bl[nf], acc[mf][nf], 0, 0, 0);
                    acc[mf][nf] = __builtin_amdgcn_mfma_f32_16x16x32_bf16(al[mf], bh[nf], acc[mf][nf], 0, 0, 0);
                }
        }
    }

    // -- epilogue: tanh + Wattn partial reduce over this block's 128 k --
    const float* h3b = h3 + b * 256;
    float part[4] = {0.f, 0.f, 0.f, 0.f};
    #pragma unroll
    for (int mf = 0; mf < 2; ++mf) {
        #pragma unroll
        for (int i = 0; i < 4; ++i) {
            int kch = r0 + w * 32 + mf * 16 + g * 4 + i;  // C/D row (m89 layout)
            float hv = h3b[kch];
            float wt = Wattn[kch];
            #pragma unroll
            for (int nf = 0; nf < 4; ++nf)
                part[nf] += wt * tanhf(acc[mf][nf][i] + hv);
        }
    }
    #pragma unroll
    for (int nf = 0; nf < 4; ++nf) {
        part[nf] += __shfl_xor(part[nf], 16, 64);
        part[nf] += __shfl_xor(part[nf], 32, 64);
    }
    if (l < 16) {
        #pragma unroll
        for (int nf = 0; nf < 4; ++nf) red2[w * 64 + nf * 16 + l] = part[nf];
    }
    __syncthreads();
    if (tid < 64) {
        float tot = red2[tid] + red2[64 + tid] + red2[128 + tid] + red2[192 + tid];
        atomicAdd(&a2[(size_t)b * 1024 + s0 + tid], tot);
    }
}

// ---------------- K3: per-batch softmax (redundant per ct-block) + context ----------------
__global__ __launch_bounds__(256) void softmax_context(const float* __restrict__ x,
                                                       const float* __restrict__ a2,
                                                       float* __restrict__ a3,
                                                       float* __restrict__ ctx) {
    __shared__ float sm[1024];
    __shared__ float red[8];
    const int tid = threadIdx.x;
    const int b = blockIdx.y, ct = blockIdx.x;
    const int wave = tid >> 6, lane = tid & 63;

    float4 v = ((const float4*)(a2 + (size_t)b * 1024))[tid];
    float m = fmaxf(fmaxf(v.x, v.y), fmaxf(v.z, v.w));
    #pragma unroll
    for (int off = 32; off >= 1; off >>= 1) m = fmaxf(m, __shfl_xor(m, off, 64));
    if (lane == 0) red[wave] = m;
    __syncthreads();
    m = fmaxf(fmaxf(red[0], red[1]), fmaxf(red[2], red[3]));
    float e0 = expf(v.x - m), e1 = expf(v.y - m), e2 = expf(v.z - m), e3 = expf(v.w - m);
    float s = e0 + e1 + e2 + e3;
    #pragma unroll
    for (int off = 32; off >= 1; off >>= 1) s += __shfl_xor(s, off, 64);
    if (lane == 0) red[4 + wave] = s;
    __syncthreads();
    s = red[4] + red[5] + red[6] + red[7];
    float inv = 1.f / s;
    float4 o = {e0 * inv, e1 * inv, e2 * inv, e3 * inv};
    ((float4*)sm)[tid] = o;
    if (ct == 0) ((float4*)(a3 + (size_t)b * 1024))[tid] = o;
    __syncthreads();

    const float* xb = x + ((size_t)b << 19);
    #pragma unroll
    for (int r = 0; r < 8; ++r) {
        int c = ct * 32 + wave * 8 + r;
        const float4* row = (const float4*)(xb + (size_t)c * 1024);
        float sum = 0.f;
        #pragma unroll
        for (int it = 0; it < 4; ++it) {
            int idx = it * 64 + lane;
            float4 xv = row[idx];
            float4 av = *(const float4*)&sm[idx * 4];
            sum = fmaf(xv.x, av.x, fmaf(xv.y, av.y, fmaf(xv.z, av.z, fmaf(xv.w, av.w, sum))));
        }
        #pragma unroll
        for (int off = 32; off >= 1; off >>= 1) sum += __shfl_xor(sum, off, 64);
        if (lane == 0) ctx[(size_t)b * 512 + c] = sum;
    }
}

extern "C" void kernel_launch(void* const* d_in, const int* in_sizes, int n_in,
                              void* d_out, int out_size, void* d_ws, size_t ws_size,
                              hipStream_t stream) {
    const float* x     = (const float*)d_in[0];
    const float* h     = (const float*)d_in[1];
    const float* Wc    = (const float*)d_in[2];
    const float* Wlin  = (const float*)d_in[3];
    const float* blin  = (const float*)d_in[4];
    const float* Wattn = (const float*)d_in[5];

    float* out = (float*)d_out;
    float* a3  = out;               // 32*1024
    float* ctx = out + 32 * 1024;   // 32*512

    char* ws = (char*)d_ws;
    float* h3 = (float*)ws;                         // 32 KB
    float* a2 = (float*)(ws + 32768);               // 128 KB
    bf16* Whi = (bf16*)(ws + 32768 + 131072);       // 256 KB
    bf16* Wlo = (bf16*)(ws + 32768 + 131072 + 262144); // 256 KB  (total 672 KB)

    hipMemsetAsync(a2, 0, 32 * 1024 * sizeof(float), stream);
    hipLaunchKernelGGL(prep_kernel, dim3(96), dim3(256), 0, stream, h, Wlin, blin, Wc, h3, Whi, Wlo);
    hipLaunchKernelGGL(fused_mfma, dim3(1024), dim3(256), 0, stream, x, Whi, Wlo, h3, Wattn, a2);
    hipLaunchKernelGGL(softmax_context, dim3(16, 32), dim3(256), 0, stream, x, a2, a3, ctx);
}

// Round 7
// 149.877 us; speedup vs baseline: 1.5146x; 1.0858x over previous
//
#include <hip/hip_runtime.h>
#include <hip/hip_bf16.h>
#include <cmath>

// AddictiveAttention: B=32, C=512, HW=1024, HID=256, MEM=256
// out = [a3: 32*1024 | context: 32*512] f32
//
// Pipeline:
//  K1 prep: h3 = h@Wlin.T + blin ; W_conv1 -> Whi/Wlo bf16 split ; zero a2
//  K2 fused_mfma: x3 = W@x via 3-term split-bf16 MFMA (register-prefetch
//     pipelined), +h3, tanh, *Wattn, k-reduce -> atomicAdd a2[b][s]
//  K3 softmax_context: softmax(a2[b]) -> a3 (ct==0 writes), context

typedef __bf16 bf16;
typedef __attribute__((ext_vector_type(8))) __bf16 bf16x8;
typedef __attribute__((ext_vector_type(4))) __bf16 bf16x4;
typedef __attribute__((ext_vector_type(4))) float f32x4;

// ---------------- K1: prep (h3 + W split + a2 zero) ----------------
__global__ __launch_bounds__(256) void prep_kernel(const float* __restrict__ h,
                                                   const float* __restrict__ Wlin,
                                                   const float* __restrict__ blin,
                                                   const float* __restrict__ Wc,
                                                   float* __restrict__ h3,
                                                   bf16* __restrict__ Whi,
                                                   bf16* __restrict__ Wlo,
                                                   float* __restrict__ a2) {
    const int tid = threadIdx.x;
    if (blockIdx.x < 32) {
        const int b = blockIdx.x;
        __shared__ float hs[256];
        hs[tid] = h[b * 256 + tid];
        __syncthreads();
        const float4* wr = (const float4*)(Wlin + (size_t)tid * 256);
        float acc = blin[tid];
        #pragma unroll 8
        for (int q = 0; q < 64; ++q) {
            float4 w = wr[q];
            float4 hv = *(const float4*)&hs[q * 4];
            acc = fmaf(w.x, hv.x, fmaf(w.y, hv.y, fmaf(w.z, hv.z, fmaf(w.w, hv.w, acc))));
        }
        h3[b * 256 + tid] = acc;
    } else {
        // W split: 64 blocks x 2048 elems
        const int e0 = (blockIdx.x - 32) * 2048 + tid * 8;
        float4 v0 = *(const float4*)(Wc + e0);
        float4 v1 = *(const float4*)(Wc + e0 + 4);
        float vs[8] = {v0.x, v0.y, v0.z, v0.w, v1.x, v1.y, v1.z, v1.w};
        bf16x8 vh, vl;
        #pragma unroll
        for (int j = 0; j < 8; ++j) {
            bf16 hi = (bf16)vs[j];
            float r = vs[j] - (float)hi;
            vh[j] = hi;
            vl[j] = (bf16)r;
        }
        *(bf16x8*)&Whi[e0] = vh;
        *(bf16x8*)&Wlo[e0] = vl;
        // a2 zero: 64 blocks x 512 floats
        float2 z = {0.f, 0.f};
        *(float2*)&a2[(blockIdx.x - 32) * 512 + tid * 2] = z;
    }
}

// ---------------- K2: split-bf16 MFMA GEMM + tanh + Wattn reduce ----------------
// Per block: m-half (128 k-chans) x 64 s-cols of one batch. 4 waves.
// Register-prefetch pipeline: {sync; regs->LDS(t); sync; load(t+1); compute(t)}.
// LDS XOR-swizzle on ushort col: ^= 8*(row&7), both write and read sides.
__global__ __launch_bounds__(256, 3) void fused_mfma(const float* __restrict__ x,
                                                     const bf16* __restrict__ Whi,
                                                     const bf16* __restrict__ Wlo,
                                                     const float* __restrict__ h3,
                                                     const float* __restrict__ Wattn,
                                                     float* __restrict__ a2) {
    __shared__ bf16 Ahi[128 * 64];
    __shared__ bf16 Alo[128 * 64];
    __shared__ bf16 Bhi[64 * 64];
    __shared__ bf16 Blo[64 * 64];
    __shared__ float red2[4 * 64];

    const int tid = threadIdx.x;
    const int bid = blockIdx.x;
    // XCD-chunked swizzle (1024 % 8 == 0 -> bijective)
    const int wk = (bid & 7) * 128 + (bid >> 3);
    const int b  = wk >> 5;
    const int st = (wk >> 1) & 15;
    const int mb = wk & 1;
    const int s0 = st * 64;
    const int r0 = mb * 128;

    const int w  = tid >> 6;   // wave 0..3 -> k-rows [w*32, w*32+32)
    const int l  = tid & 63;
    const int g  = l >> 4;     // k-group within frag
    const int lr = l & 15;

    const float* xb = x + ((size_t)b << 19);

    f32x4 acc[2][4];
    #pragma unroll
    for (int mf = 0; mf < 2; ++mf)
        #pragma unroll
        for (int nf = 0; nf < 4; ++nf)
            acc[mf][nf] = (f32x4){0.f, 0.f, 0.f, 0.f};

    // A staging geometry: row = tid>>3 (+32jj), col chunk = (tid&7)*8
    const int arow_ = tid >> 3;
    const int acol  = (tid & 7) * 8;
    // B staging geometry: sp = (tid&15)*4 (4 s-vals), cb = (tid>>4)*4 (4 c-rows via jj)
    const int sp = (tid & 15) * 4;
    const int cb = (tid >> 4) * 4;

    // in-flight staging registers
    bf16x8 wva[4], wvl[4];
    float4 xv[4];

    // ---- prologue: load tile 0 ----
    #pragma unroll
    for (int jj = 0; jj < 4; ++jj) {
        int row = arow_ + 32 * jj;
        size_t off = (size_t)(r0 + row) * 512 + acol;
        wva[jj] = *(const bf16x8*)(Whi + off);
        wvl[jj] = *(const bf16x8*)(Wlo + off);
    }
    #pragma unroll
    for (int jj = 0; jj < 4; ++jj)
        xv[jj] = *(const float4*)(xb + (size_t)(cb + jj) * 1024 + s0 + sp);

    #pragma unroll 1
    for (int c0 = 0; c0 < 512; c0 += 64) {
        __syncthreads();  // previous tile's compute done; LDS free
        // ---- regs -> LDS (swizzled) ----
        #pragma unroll
        for (int jj = 0; jj < 4; ++jj) {
            int row = arow_ + 32 * jj;
            int idx = row * 64 + (acol ^ (8 * (row & 7)));
            *(bf16x8*)&Ahi[idx] = wva[jj];
            *(bf16x8*)&Alo[idx] = wvl[jj];
        }
        {
            // convert 4x4 f32 block -> bf16 hi/lo, write 4 s-rows as b64
            bf16 hi[4][4], lo[4][4];  // [jj(c)][ss(s)]
            #pragma unroll
            for (int jj = 0; jj < 4; ++jj) {
                float vv[4] = {xv[jj].x, xv[jj].y, xv[jj].z, xv[jj].w};
                #pragma unroll
                for (int ss = 0; ss < 4; ++ss) {
                    bf16 hh = (bf16)vv[ss];
                    hi[jj][ss] = hh;
                    lo[jj][ss] = (bf16)(vv[ss] - (float)hh);
                }
            }
            #pragma unroll
            for (int ss = 0; ss < 4; ++ss) {
                int row = sp + ss;
                int idx = row * 64 + (cb ^ (8 * (row & 7)));
                bf16x4 ph = {hi[0][ss], hi[1][ss], hi[2][ss], hi[3][ss]};
                bf16x4 pl = {lo[0][ss], lo[1][ss], lo[2][ss], lo[3][ss]};
                *(bf16x4*)&Bhi[idx] = ph;
                *(bf16x4*)&Blo[idx] = pl;
            }
        }
        __syncthreads();  // tile ready
        // ---- issue next tile's global loads (overlap with compute below) ----
        if (c0 + 64 < 512) {
            #pragma unroll
            for (int jj = 0; jj < 4; ++jj) {
                int row = arow_ + 32 * jj;
                size_t off = (size_t)(r0 + row) * 512 + (c0 + 64) + acol;
                wva[jj] = *(const bf16x8*)(Whi + off);
                wvl[jj] = *(const bf16x8*)(Wlo + off);
            }
            #pragma unroll
            for (int jj = 0; jj < 4; ++jj)
                xv[jj] = *(const float4*)(xb + (size_t)(c0 + 64 + cb + jj) * 1024 + s0 + sp);
        }
        // ---- compute: 2 K-steps x (2 mf x 4 nf x 3 terms) MFMA ----
        #pragma unroll
        for (int kk = 0; kk < 2; ++kk) {
            bf16x8 ah[2], al[2], bh[4], bl[4];
            #pragma unroll
            for (int mf = 0; mf < 2; ++mf) {
                int row = w * 32 + mf * 16 + lr;
                int idx = row * 64 + ((kk * 32 + 8 * g) ^ (8 * (row & 7)));
                ah[mf] = *(const bf16x8*)&Ahi[idx];
                al[mf] = *(const bf16x8*)&Alo[idx];
            }
            #pragma unroll
            for (int nf = 0; nf < 4; ++nf) {
                int srow = nf * 16 + lr;
                int idx = srow * 64 + ((kk * 32 + 8 * g) ^ (8 * (srow & 7)));
                bh[nf] = *(const bf16x8*)&Bhi[idx];
                bl[nf] = *(const bf16x8*)&Blo[idx];
            }
            #pragma unroll
            for (int mf = 0; mf < 2; ++mf)
                #pragma unroll
                for (int nf = 0; nf < 4; ++nf) {
                    acc[mf][nf] = __builtin_amdgcn_mfma_f32_16x16x32_bf16(ah[mf], bh[nf], acc[mf][nf], 0, 0, 0);
                    acc[mf][nf] = __builtin_amdgcn_mfma_f32_16x16x32_bf16(ah[mf], bl[nf], acc[mf][nf], 0, 0, 0);
                    acc[mf][nf] = __builtin_amdgcn_mfma_f32_16x16x32_bf16(al[mf], bh[nf], acc[mf][nf], 0, 0, 0);
                }
        }
    }

    // ---- epilogue: tanh + Wattn partial reduce over this block's 128 k ----
    const float* h3b = h3 + b * 256;
    float part[4] = {0.f, 0.f, 0.f, 0.f};
    #pragma unroll
    for (int mf = 0; mf < 2; ++mf) {
        #pragma unroll
        for (int i = 0; i < 4; ++i) {
            int kch = r0 + w * 32 + mf * 16 + g * 4 + i;  // C/D row (m89 layout)
            float hv = h3b[kch];
            float wt = Wattn[kch];
            #pragma unroll
            for (int nf = 0; nf < 4; ++nf)
                part[nf] += wt * tanhf(acc[mf][nf][i] + hv);
        }
    }
    #pragma unroll
    for (int nf = 0; nf < 4; ++nf) {
        part[nf] += __shfl_xor(part[nf], 16, 64);
        part[nf] += __shfl_xor(part[nf], 32, 64);
    }
    if (l < 16) {
        #pragma unroll
        for (int nf = 0; nf < 4; ++nf) red2[w * 64 + nf * 16 + l] = part[nf];
    }
    __syncthreads();
    if (tid < 64) {
        float tot = red2[tid] + red2[64 + tid] + red2[128 + tid] + red2[192 + tid];
        atomicAdd(&a2[(size_t)b * 1024 + s0 + tid], tot);
    }
}

// ---------------- K3: per-batch softmax (redundant per ct-block) + context ----------------
__global__ __launch_bounds__(256) void softmax_context(const float* __restrict__ x,
                                                       const float* __restrict__ a2,
                                                       float* __restrict__ a3,
                                                       float* __restrict__ ctx) {
    __shared__ float sm[1024];
    __shared__ float red[8];
    const int tid = threadIdx.x;
    const int b = blockIdx.y, ct = blockIdx.x;  // 32 ct x 16 rows
    const int wave = tid >> 6, lane = tid & 63;

    float4 v = ((const float4*)(a2 + (size_t)b * 1024))[tid];
    float m = fmaxf(fmaxf(v.x, v.y), fmaxf(v.z, v.w));
    #pragma unroll
    for (int off = 32; off >= 1; off >>= 1) m = fmaxf(m, __shfl_xor(m, off, 64));
    if (lane == 0) red[wave] = m;
    __syncthreads();
    m = fmaxf(fmaxf(red[0], red[1]), fmaxf(red[2], red[3]));
    float e0 = expf(v.x - m), e1 = expf(v.y - m), e2 = expf(v.z - m), e3 = expf(v.w - m);
    float s = e0 + e1 + e2 + e3;
    #pragma unroll
    for (int off = 32; off >= 1; off >>= 1) s += __shfl_xor(s, off, 64);
    if (lane == 0) red[4 + wave] = s;
    __syncthreads();
    s = red[4] + red[5] + red[6] + red[7];
    float inv = 1.f / s;
    float4 o = {e0 * inv, e1 * inv, e2 * inv, e3 * inv};
    ((float4*)sm)[tid] = o;
    if (ct == 0) ((float4*)(a3 + (size_t)b * 1024))[tid] = o;
    __syncthreads();

    const float* xb = x + ((size_t)b << 19);
    #pragma unroll
    for (int r = 0; r < 4; ++r) {
        int c = ct * 16 + wave * 4 + r;
        const float4* row = (const float4*)(xb + (size_t)c * 1024);
        float sum = 0.f;
        #pragma unroll
        for (int it = 0; it < 4; ++it) {
            int idx = it * 64 + lane;
            float4 xv = row[idx];
            float4 av = *(const float4*)&sm[idx * 4];
            sum = fmaf(xv.x, av.x, fmaf(xv.y, av.y, fmaf(xv.z, av.z, fmaf(xv.w, av.w, sum))));
        }
        #pragma unroll
        for (int off = 32; off >= 1; off >>= 1) sum += __shfl_xor(sum, off, 64);
        if (lane == 0) ctx[(size_t)b * 512 + c] = sum;
    }
}

extern "C" void kernel_launch(void* const* d_in, const int* in_sizes, int n_in,
                              void* d_out, int out_size, void* d_ws, size_t ws_size,
                              hipStream_t stream) {
    const float* x     = (const float*)d_in[0];
    const float* h     = (const float*)d_in[1];
    const float* Wc    = (const float*)d_in[2];
    const float* Wlin  = (const float*)d_in[3];
    const float* blin  = (const float*)d_in[4];
    const float* Wattn = (const float*)d_in[5];

    float* out = (float*)d_out;
    float* a3  = out;               // 32*1024
    float* ctx = out + 32 * 1024;   // 32*512

    char* ws = (char*)d_ws;
    float* h3 = (float*)ws;                         // 32 KB
    float* a2 = (float*)(ws + 32768);               // 128 KB
    bf16* Whi = (bf16*)(ws + 32768 + 131072);       // 256 KB
    bf16* Wlo = (bf16*)(ws + 32768 + 131072 + 262144); // 256 KB  (total 672 KB)

    hipLaunchKernelGGL(prep_kernel, dim3(96), dim3(256), 0, stream, h, Wlin, blin, Wc, h3, Whi, Wlo, a2);
    hipLaunchKernelGGL(fused_mfma, dim3(1024), dim3(256), 0, stream, x, Whi, Wlo, h3, Wattn, a2);
    hipLaunchKernelGGL(softmax_context, dim3(32, 32), dim3(256), 0, stream, x, a2, a3, ctx);
}